// Round 1
// baseline (53.162 us; speedup 1.0000x reference)
//
#include <hip/hip_runtime.h>

// LowPassMSELoss: mean((lfilter(b,a,output) - lfilter(b,a,target))^2)
// Linearity: = mean(lfilter(b,a,output-target)^2).
// Chunked parallel IIR: poles of this Butterworth have |p|max ~ 0.869, so a
// 256-sample zero-state warm-up reconstructs the state to ~2e-16 relative.

#define CHUNK 512
#define WARM  256

__global__ __launch_bounds__(64) void lp_iir_partial(
    const float* __restrict__ outp, const float* __restrict__ tgtp,
    const float* __restrict__ bp, const float* __restrict__ ap,
    float* __restrict__ partial, int T, int chunks_per_row)
{
    const int gid = blockIdx.x * 64 + threadIdx.x;
    const int row = gid / chunks_per_row;
    const int ci  = gid - row * chunks_per_row;
    const long base = (long)row * T;
    const int s  = ci * CHUNK;
    const int w0 = (s >= WARM) ? (s - WARM) : 0;

    // normalized coefficients (a[0] is 1.0 from np.poly, normalize anyway)
    const float a0inv = 1.0f / ap[0];
    const float bb0 = bp[0]*a0inv, bb1 = bp[1]*a0inv, bb2 = bp[2]*a0inv,
                bb3 = bp[3]*a0inv, bb4 = bp[4]*a0inv, bb5 = bp[5]*a0inv,
                bb6 = bp[6]*a0inv;
    const float na1 = -ap[1]*a0inv, na2 = -ap[2]*a0inv, na3 = -ap[3]*a0inv,
                na4 = -ap[4]*a0inv, na5 = -ap[5]*a0inv, na6 = -ap[6]*a0inv;

    float z0=0.f,z1=0.f,z2=0.f,z3=0.f,z4=0.f,z5=0.f;
    const float4* o4 = reinterpret_cast<const float4*>(outp) + (base >> 2);
    const float4* t4 = reinterpret_cast<const float4*>(tgtp) + (base >> 2);

    float acc = 0.0f;
    float yv = 0.0f;

    // Direct-form II transposed, order 6:
    //   y  = b0*x + z0
    //   zi = z(i+1) + b(i+1)*x - a(i+1)*y   (z6 == 0)
#define STEP(X) do { \
    const float x = (X); \
    const float y = fmaf(bb0, x, z0); \
    z0 = fmaf(na1, y, fmaf(bb1, x, z1)); \
    z1 = fmaf(na2, y, fmaf(bb2, x, z2)); \
    z2 = fmaf(na3, y, fmaf(bb3, x, z3)); \
    z3 = fmaf(na4, y, fmaf(bb4, x, z4)); \
    z4 = fmaf(na5, y, fmaf(bb5, x, z5)); \
    z5 = fmaf(na6, y, bb6*x); \
    yv = y; } while (0)

    int t = w0;
    for (; t < s; t += 4) {              // warm-up: run filter, discard y
        const float4 ov = o4[t>>2], tv = t4[t>>2];
        STEP(ov.x - tv.x); STEP(ov.y - tv.y);
        STEP(ov.z - tv.z); STEP(ov.w - tv.w);
    }
    const int e = s + CHUNK;
    for (; t < e; t += 4) {              // main: accumulate y^2
        const float4 ov = o4[t>>2], tv = t4[t>>2];
        STEP(ov.x - tv.x); acc = fmaf(yv, yv, acc);
        STEP(ov.y - tv.y); acc = fmaf(yv, yv, acc);
        STEP(ov.z - tv.z); acc = fmaf(yv, yv, acc);
        STEP(ov.w - tv.w); acc = fmaf(yv, yv, acc);
    }
#undef STEP

    // wave (=block) reduction, deterministic
    #pragma unroll
    for (int off = 32; off > 0; off >>= 1)
        acc += __shfl_down(acc, off);
    if (threadIdx.x == 0) partial[blockIdx.x] = acc;
}

__global__ __launch_bounds__(64) void lp_final(
    const float* __restrict__ partial, int n, float* __restrict__ dst, float scale)
{
    float v = 0.0f;
    for (int i = threadIdx.x; i < n; i += 64) v += partial[i];
    #pragma unroll
    for (int off = 32; off > 0; off >>= 1)
        v += __shfl_down(v, off);
    if (threadIdx.x == 0) dst[0] = v * scale;
}

extern "C" void kernel_launch(void* const* d_in, const int* in_sizes, int n_in,
                              void* d_out, int out_size, void* d_ws, size_t ws_size,
                              hipStream_t stream) {
    const float* outp = (const float*)d_in[0];
    const float* tgtp = (const float*)d_in[1];
    const float* bp   = (const float*)d_in[2];
    const float* ap   = (const float*)d_in[3];

    const int T = 262144;                 // time axis length (reference shape)
    const int B = in_sizes[0] / T;        // 16
    const int chunks_per_row = T / CHUNK; // 512
    const int total = B * chunks_per_row; // 8192 threads
    const int nblocks = total / 64;       // 128 blocks of one wave each

    float* partial = (float*)d_ws;

    lp_iir_partial<<<nblocks, 64, 0, stream>>>(outp, tgtp, bp, ap, partial,
                                               T, chunks_per_row);
    lp_final<<<1, 64, 0, stream>>>(partial, nblocks, (float*)d_out,
                                   1.0f / (float)(B * T));
}

// Round 2
// 38.402 us; speedup vs baseline: 1.3844x; 1.3844x over previous
//
#include <hip/hip_runtime.h>

// LowPassMSELoss: mean((lfilter(b,a,output) - lfilter(b,a,target))^2)
//               = mean(lfilter(b,a,output-target)^2)   (linearity, zero state)
// Chunked parallel IIR: |pole|max ~ 0.869 -> WARM=128 warm-up gives ~e^-18
// relative state error. Chunks 0,1 of each row are EXACT via zero-padding
// (x=0 for t<0 keeps the zero state invariant).
// M=2 independent chunks per thread, interleaved, + 1-iter prefetch for MLP.

#define CHUNK 64
#define WARM  128
#define NW (WARM / 4)   // 32 warm iterations
#define NM (CHUNK / 4)  // 16 main iterations
#define M  2

#define DECLC(m) \
    long base##m; int t##m; \
    float z0##m = 0.f, z1##m = 0.f, z2##m = 0.f, z3##m = 0.f, \
          z4##m = 0.f, z5##m = 0.f, yv##m = 0.f;

#define SETUP(m, cidx) { \
    const int c = (cidx); \
    const int r = c / chunks_per_row; \
    const int ci = c - r * chunks_per_row; \
    base##m = (long)r * T; \
    t##m = ci * CHUNK - WARM; }

#define LOADX(m, dst) { \
    const int tt = t##m; \
    const int tc = tt < 0 ? 0 : tt; \
    long i4 = (base##m + tc) >> 2; \
    if (i4 > max4) i4 = max4; \
    const float4 ov = o4[i4], tv = tg4[i4]; \
    dst.x = ov.x - tv.x; dst.y = ov.y - tv.y; \
    dst.z = ov.z - tv.z; dst.w = ov.w - tv.w; \
    if (tt < 0) { dst.x = 0.f; dst.y = 0.f; dst.z = 0.f; dst.w = 0.f; } }

// Direct-form II transposed, order 6 (z6 == 0)
#define STEP(m, X) { \
    const float xx = (X); \
    const float y = fmaf(bb0, xx, z0##m); \
    z0##m = fmaf(na1, y, fmaf(bb1, xx, z1##m)); \
    z1##m = fmaf(na2, y, fmaf(bb2, xx, z2##m)); \
    z2##m = fmaf(na3, y, fmaf(bb3, xx, z3##m)); \
    z3##m = fmaf(na4, y, fmaf(bb4, xx, z4##m)); \
    z4##m = fmaf(na5, y, fmaf(bb5, xx, z5##m)); \
    z5##m = fmaf(na6, y, bb6 * xx); \
    yv##m = y; }

#define STEP4(m, V)  { STEP(m, V.x) STEP(m, V.y) STEP(m, V.z) STEP(m, V.w) }
#define STEP4A(m, V) { STEP(m, V.x) acc = fmaf(yv##m, yv##m, acc); \
                       STEP(m, V.y) acc = fmaf(yv##m, yv##m, acc); \
                       STEP(m, V.z) acc = fmaf(yv##m, yv##m, acc); \
                       STEP(m, V.w) acc = fmaf(yv##m, yv##m, acc); }

__global__ __launch_bounds__(64) void lp_iir_partial(
    const float* __restrict__ outp, const float* __restrict__ tgtp,
    const float* __restrict__ bp, const float* __restrict__ ap,
    float* __restrict__ partial, int T, int chunks_per_row,
    int nthreads, long max4)
{
    const int tid = blockIdx.x * 64 + threadIdx.x;

    const float a0inv = 1.0f / ap[0];
    const float bb0 = bp[0]*a0inv, bb1 = bp[1]*a0inv, bb2 = bp[2]*a0inv,
                bb3 = bp[3]*a0inv, bb4 = bp[4]*a0inv, bb5 = bp[5]*a0inv,
                bb6 = bp[6]*a0inv;
    const float na1 = -ap[1]*a0inv, na2 = -ap[2]*a0inv, na3 = -ap[3]*a0inv,
                na4 = -ap[4]*a0inv, na5 = -ap[5]*a0inv, na6 = -ap[6]*a0inv;

    const float4* o4  = reinterpret_cast<const float4*>(outp);
    const float4* tg4 = reinterpret_cast<const float4*>(tgtp);

    DECLC(0) DECLC(1)
    SETUP(0, tid)
    SETUP(1, tid + nthreads)

    float acc = 0.f;
    float4 x0c, x1c, x0n, x1n;
    LOADX(0, x0c) LOADX(1, x1c)

    #pragma unroll 4
    for (int it = 0; it < NW; ++it) {       // warm-up: discard y
        t0 += 4; t1 += 4;
        LOADX(0, x0n) LOADX(1, x1n)
        STEP4(0, x0c) STEP4(1, x1c)
        x0c = x0n; x1c = x1n;
    }
    #pragma unroll 4
    for (int it = 0; it < NM - 1; ++it) {   // main: accumulate y^2
        t0 += 4; t1 += 4;
        LOADX(0, x0n) LOADX(1, x1n)
        STEP4A(0, x0c) STEP4A(1, x1c)
        x0c = x0n; x1c = x1n;
    }
    STEP4A(0, x0c) STEP4A(1, x1c)           // last iter, no prefetch

    #pragma unroll
    for (int off = 32; off > 0; off >>= 1)
        acc += __shfl_down(acc, off);
    if (threadIdx.x == 0) partial[blockIdx.x] = acc;
}

__global__ __launch_bounds__(64) void lp_final(
    const float* __restrict__ partial, int n, float* __restrict__ dst, float scale)
{
    float v = 0.0f;
    for (int i = threadIdx.x; i < n; i += 64) v += partial[i];
    #pragma unroll
    for (int off = 32; off > 0; off >>= 1)
        v += __shfl_down(v, off);
    if (threadIdx.x == 0) dst[0] = v * scale;
}

extern "C" void kernel_launch(void* const* d_in, const int* in_sizes, int n_in,
                              void* d_out, int out_size, void* d_ws, size_t ws_size,
                              hipStream_t stream) {
    const float* outp = (const float*)d_in[0];
    const float* tgtp = (const float*)d_in[1];
    const float* bp   = (const float*)d_in[2];
    const float* ap   = (const float*)d_in[3];

    const int T = 262144;
    const int B = in_sizes[0] / T;                 // 16
    const int chunks_per_row = T / CHUNK;          // 4096
    const int total_chunks = B * chunks_per_row;   // 65536
    const int nthreads = total_chunks / M;         // 32768
    const int nblocks = nthreads / 64;             // 512 blocks (1 wave each)
    const long max4 = ((long)B * T) / 4 - 1;

    float* partial = (float*)d_ws;

    lp_iir_partial<<<nblocks, 64, 0, stream>>>(outp, tgtp, bp, ap, partial,
                                               T, chunks_per_row, nthreads, max4);
    lp_final<<<1, 64, 0, stream>>>(partial, nblocks, (float*)d_out,
                                   1.0f / ((float)B * (float)T));
}

// Round 3
// 28.240 us; speedup vs baseline: 1.8825x; 1.3598x over previous
//
#include <hip/hip_runtime.h>

// LowPassMSELoss: mean((lfilter(b,a,output) - lfilter(b,a,target))^2)
//               = mean(lfilter(b,a,output-target)^2)   (linearity, zero state)
//
// Stage 1 (prepass): diff = output - target written to a padded layout
//   [B][WARM zeros + T samples]  -> removes clamp logic + one load stream
//   from the IIR loop, and leaves diff L2/L3-resident.
// Stage 2 (IIR): chunked parallel IIR. |pole|max = 0.869 -> WARM=96 gives
//   0.869^96 ~ 1.4e-6 relative state error (threshold is 7.3e-3).
// Stage 3: reduce partials.

#define TT   262144          // time length (fixed by reference)
#define T4   (TT/4)
#define WARM 96
#define W4   (WARM/4)        // 24
#define CHUNK 32
#define C4   (CHUNK/4)       // 8
#define TP   (TT + WARM)
#define TP4  (TP/4)          // 65560
#define CPR  (TT/CHUNK)      // 8192 chunks per row

__global__ __launch_bounds__(256) void lp_prepass(
    const float4* __restrict__ o4, const float4* __restrict__ t4,
    float4* __restrict__ w4, int total4)
{
    int idx = blockIdx.x * 256 + threadIdx.x;
    const int stride = gridDim.x * 256;
    for (; idx < total4; idx += stride) {
        const int row = idx / TP4;          // constant div -> magic mul
        const int pc4 = idx - row * TP4;
        const int s4  = pc4 - W4;
        float4 v = make_float4(0.f, 0.f, 0.f, 0.f);
        if (s4 >= 0) {
            const float4 a = o4[row * T4 + s4];
            const float4 b = t4[row * T4 + s4];
            v.x = a.x - b.x; v.y = a.y - b.y;
            v.z = a.z - b.z; v.w = a.w - b.w;
        }
        w4[idx] = v;
    }
}

// Direct-form II transposed, order 6 (z6 == 0)
#define STEP(X) { \
    const float xx = (X); \
    const float y = fmaf(bb0, xx, z0); \
    z0 = fmaf(na1, y, fmaf(bb1, xx, z1)); \
    z1 = fmaf(na2, y, fmaf(bb2, xx, z2)); \
    z2 = fmaf(na3, y, fmaf(bb3, xx, z3)); \
    z3 = fmaf(na4, y, fmaf(bb4, xx, z4)); \
    z4 = fmaf(na5, y, fmaf(bb5, xx, z5)); \
    z5 = fmaf(na6, y, bb6 * xx); \
    yv = y; }

__global__ __launch_bounds__(256) void lp_iir(
    const float4* __restrict__ w4,
    const float* __restrict__ bp, const float* __restrict__ ap,
    float* __restrict__ partial)
{
    const int tid = blockIdx.x * 256 + threadIdx.x;
    const int row = tid >> 13;              // / CPR (8192)
    const int ci  = tid & (CPR - 1);

    const float a0inv = 1.0f / ap[0];
    const float bb0 = bp[0]*a0inv, bb1 = bp[1]*a0inv, bb2 = bp[2]*a0inv,
                bb3 = bp[3]*a0inv, bb4 = bp[4]*a0inv, bb5 = bp[5]*a0inv,
                bb6 = bp[6]*a0inv;
    const float na1 = -ap[1]*a0inv, na2 = -ap[2]*a0inv, na3 = -ap[3]*a0inv,
                na4 = -ap[4]*a0inv, na5 = -ap[5]*a0inv, na6 = -ap[6]*a0inv;

    const float4* __restrict__ p = w4 + row * TP4 + ci * C4;

    float z0 = 0.f, z1 = 0.f, z2 = 0.f, z3 = 0.f, z4 = 0.f, z5 = 0.f;
    float yv = 0.f, acc = 0.f;

    #pragma unroll
    for (int it = 0; it < W4 + C4; ++it) {  // 32 f4 iterations, fully unrolled
        const float4 x = p[it];
        if (it < W4) {                       // warm-up: discard y
            STEP(x.x) STEP(x.y) STEP(x.z) STEP(x.w)
        } else {                             // main: accumulate y^2
            STEP(x.x) acc = fmaf(yv, yv, acc);
            STEP(x.y) acc = fmaf(yv, yv, acc);
            STEP(x.z) acc = fmaf(yv, yv, acc);
            STEP(x.w) acc = fmaf(yv, yv, acc);
        }
    }

    // wave reduction
    #pragma unroll
    for (int off = 32; off > 0; off >>= 1)
        acc += __shfl_down(acc, off);

    __shared__ float red[4];
    const int wid = threadIdx.x >> 6;
    if ((threadIdx.x & 63) == 0) red[wid] = acc;
    __syncthreads();
    if (threadIdx.x == 0)
        partial[blockIdx.x] = red[0] + red[1] + red[2] + red[3];
}

__global__ __launch_bounds__(64) void lp_final(
    const float* __restrict__ partial, int n, float* __restrict__ dst, float scale)
{
    float v = 0.0f;
    for (int i = threadIdx.x; i < n; i += 64) v += partial[i];
    #pragma unroll
    for (int off = 32; off > 0; off >>= 1)
        v += __shfl_down(v, off);
    if (threadIdx.x == 0) dst[0] = v * scale;
}

extern "C" void kernel_launch(void* const* d_in, const int* in_sizes, int n_in,
                              void* d_out, int out_size, void* d_ws, size_t ws_size,
                              hipStream_t stream) {
    const float* outp = (const float*)d_in[0];
    const float* tgtp = (const float*)d_in[1];
    const float* bp   = (const float*)d_in[2];
    const float* ap   = (const float*)d_in[3];

    const int B = in_sizes[0] / TT;              // 16
    const int total4 = B * TP4;                  // padded f4 count
    const int nthreads = B * CPR;                // 131072 (one per chunk)
    const int nblocks = nthreads / 256;          // 512

    float4* w4 = (float4*)d_ws;
    float* partial = (float*)((char*)d_ws + (size_t)total4 * sizeof(float4));

    lp_prepass<<<1024, 256, 0, stream>>>(
        (const float4*)outp, (const float4*)tgtp, w4, total4);
    lp_iir<<<nblocks, 256, 0, stream>>>(w4, bp, ap, partial);
    lp_final<<<1, 64, 0, stream>>>(partial, nblocks, (float*)d_out,
                                   1.0f / ((float)B * (float)TT));
}